// Round 7
// baseline (2463.616 us; speedup 1.0000x reference)
//
#include <hip/hip_runtime.h>

#define Bsz 16
#define Tl  4096
#define NUc 64
#define NXc 256
#define NYc 32

// ---------------------------------------------------------------------------
// DPP cross-lane reductions (pure VALU, no LDS pipe).
// ---------------------------------------------------------------------------
template <int CTRL>
__device__ __forceinline__ float dpp_add(float x) {
    int y = __builtin_amdgcn_update_dpp(0, __float_as_int(x), CTRL, 0xf, 0xf, true);
    return x + __int_as_float(y);
}
__device__ __forceinline__ float row_reduce16(float x) {
    x = dpp_add<0x128>(x);   // row_ror:8
    x = dpp_add<0x124>(x);   // row_ror:4
    x = dpp_add<0x4E>(x);    // quad_perm xor2
    x = dpp_add<0xB1>(x);    // quad_perm xor1
    return x;
}

// keep-alive on a NAMED scalar
#define KEEPF(x) asm volatile("" : "+v"(x))

// ---------------- per-chunk weight macros (4 floats each) ------------------
#define DECLC(T,J) float W##T##J##_0, W##T##J##_1, W##T##J##_2, W##T##J##_3
#define LOADC(T,J,P) { float4 v_ = *(const float4*)(P); \
    W##T##J##_0=v_.x; W##T##J##_1=v_.y; W##T##J##_2=v_.z; W##T##J##_3=v_.w; }
#define PINC(T,J) KEEPF(W##T##J##_0); KEEPF(W##T##J##_1); \
                  KEEPF(W##T##J##_2); KEEPF(W##T##J##_3)
#define FMAC(T,J,Q,AC) \
    AC=fmaf(W##T##J##_0,(Q).x,AC); AC=fmaf(W##T##J##_1,(Q).y,AC); \
    AC=fmaf(W##T##J##_2,(Q).z,AC); AC=fmaf(W##T##J##_3,(Q).w,AC)

#define DECLROW(T) DECLC(T,0); DECLC(T,1); DECLC(T,2); DECLC(T,3); \
                   DECLC(T,4); DECLC(T,5); DECLC(T,6); DECLC(T,7)
#define LOADROW(T,BASE) \
    LOADC(T,0,(BASE)+4*p0); LOADC(T,1,(BASE)+4*p1); \
    LOADC(T,2,(BASE)+4*p2); LOADC(T,3,(BASE)+4*p3); \
    LOADC(T,4,(BASE)+4*p4); LOADC(T,5,(BASE)+4*p5); \
    LOADC(T,6,(BASE)+4*p6); LOADC(T,7,(BASE)+4*p7)
#define PINROW(T) PINC(T,0); PINC(T,1); PINC(T,2); PINC(T,3); \
                  PINC(T,4); PINC(T,5); PINC(T,6); PINC(T,7)
// j=1..7 into two chains (even j -> A0 which carries c-chunk, odd j -> A1)
#define FMAROW(T,A0,A1) \
    FMAC(T,1,Q1,A1); FMAC(T,2,Q2,A0); FMAC(T,3,Q3,A1); FMAC(T,4,Q4,A0); \
    FMAC(T,5,Q5,A1); FMAC(T,6,Q6,A0); FMAC(T,7,Q7,A1)
// own-chunk (j=0) carry: 4-deep FMA chain
#define CARRY4(T,Q) c##T = fmaf(W##T##0_3,(Q).w, fmaf(W##T##0_2,(Q).z, \
                     fmaf(W##T##0_1,(Q).y, W##T##0_0*(Q).x)))

// inline-K fallback: 8 u-weights per row
#define DECLK8(T) float kk##T##_0,kk##T##_1,kk##T##_2,kk##T##_3,kk##T##_4,kk##T##_5,kk##T##_6,kk##T##_7
#define LOADK8(T,RP) { \
    float4 a_=*(const float4*)(RP), b_=*(const float4*)((RP)+4); \
    kk##T##_0=a_.x; kk##T##_1=a_.y; kk##T##_2=a_.z; kk##T##_3=a_.w; \
    kk##T##_4=b_.x; kk##T##_5=b_.y; kk##T##_6=b_.z; kk##T##_7=b_.w; }
#define PINK8(T) \
    KEEPF(kk##T##_0); KEEPF(kk##T##_1); KEEPF(kk##T##_2); KEEPF(kk##T##_3); \
    KEEPF(kk##T##_4); KEEPF(kk##T##_5); KEEPF(kk##T##_6); KEEPF(kk##T##_7)
#define FMAK8(T,AC0,AC1) \
    AC0=fmaf(kk##T##_0,uu0.x,AC0); AC1=fmaf(kk##T##_1,uu0.y,AC1); \
    AC0=fmaf(kk##T##_2,uu0.z,AC0); AC1=fmaf(kk##T##_3,uu0.w,AC1); \
    AC0=fmaf(kk##T##_4,uu1.x,AC0); AC1=fmaf(kk##T##_5,uu1.y,AC1); \
    AC0=fmaf(kk##T##_6,uu1.z,AC0); AC1=fmaf(kk##T##_7,uu1.w,AC1)

// ---------------------------------------------------------------------------
// Ku[row, x] = sum_u inputs[row, u] * K_w[x, u]   (parallel, full GPU)
// ---------------------------------------------------------------------------
#define KDECL4(Q)  float k##Q##_0, k##Q##_1, k##Q##_2, k##Q##_3
#define KLOAD4(Q) { float4 v_ = *(const float4*)(wr_ + 4*Q); \
    k##Q##_0 = v_.x; k##Q##_1 = v_.y; k##Q##_2 = v_.z; k##Q##_3 = v_.w; }
#define KPIN4(Q)   KEEPF(k##Q##_0); KEEPF(k##Q##_1); KEEPF(k##Q##_2); KEEPF(k##Q##_3)
#define KACC4(Q, U) { \
    s0_ = fmaf(k##Q##_0, (U).x, s0_); s1_ = fmaf(k##Q##_1, (U).y, s1_); \
    s0_ = fmaf(k##Q##_2, (U).z, s0_); s1_ = fmaf(k##Q##_3, (U).w, s1_); }

__global__ __launch_bounds__(256) void ku_kernel(const float* __restrict__ inputs,
                                                 const float* __restrict__ Kw,
                                                 float* __restrict__ Ku) {
    const int x    = threadIdx.x;
    const int row0 = blockIdx.x * 64;

    const float* wr_ = Kw + (size_t)x * NUc;
    KDECL4(0);  KDECL4(1);  KDECL4(2);  KDECL4(3);
    KDECL4(4);  KDECL4(5);  KDECL4(6);  KDECL4(7);
    KDECL4(8);  KDECL4(9);  KDECL4(10); KDECL4(11);
    KDECL4(12); KDECL4(13); KDECL4(14); KDECL4(15);
    KLOAD4(0);  KLOAD4(1);  KLOAD4(2);  KLOAD4(3);
    KLOAD4(4);  KLOAD4(5);  KLOAD4(6);  KLOAD4(7);
    KLOAD4(8);  KLOAD4(9);  KLOAD4(10); KLOAD4(11);
    KLOAD4(12); KLOAD4(13); KLOAD4(14); KLOAD4(15);
    KPIN4(0);  KPIN4(1);  KPIN4(2);  KPIN4(3);
    KPIN4(4);  KPIN4(5);  KPIN4(6);  KPIN4(7);
    KPIN4(8);  KPIN4(9);  KPIN4(10); KPIN4(11);
    KPIN4(12); KPIN4(13); KPIN4(14); KPIN4(15);

    __shared__ float sin_[64 * NUc];     // 16 KB
    {
        const float* src = inputs + (size_t)row0 * NUc;
        #pragma unroll
        for (int i = 0; i < 16; ++i)
            sin_[threadIdx.x + i * 256] = src[threadIdx.x + i * 256];
    }
    __syncthreads();

    for (int r = 0; r < 64; ++r) {
        const float4* hp = (const float4*)(&sin_[r * NUc]);  // wave-uniform
        float s0_ = 0.f, s1_ = 0.f;
        KACC4(0,  hp[0]);  KACC4(1,  hp[1]);  KACC4(2,  hp[2]);  KACC4(3,  hp[3]);
        KACC4(4,  hp[4]);  KACC4(5,  hp[5]);  KACC4(6,  hp[6]);  KACC4(7,  hp[7]);
        KACC4(8,  hp[8]);  KACC4(9,  hp[9]);  KACC4(10, hp[10]); KACC4(11, hp[11]);
        KACC4(12, hp[12]); KACC4(13, hp[13]); KACC4(14, hp[14]); KACC4(15, hp[15]);
        Ku[(size_t)(row0 + r) * NXc + x] = s0_ + s1_;
    }
}

// ---------------------------------------------------------------------------
// Scan v5: one block per batch, 512 threads (8 waves, 2/SIMD).
// lane (c=tid&7, jg=tid>>3): rows 4jg..4jg+3, 32 cols as 8 PERMUTED float4
// positions p_j=(8w+8j+c)&63 (w=wave). p_0 lies in the wave's OWN rows, so
// after writing h each wave reads+FMAs its own chunk BEFORE the barrier
// (same-wave LDS visibility, lgkmcnt only) — hiding the write drain and one
// read latency in the former stall. Unroll x2 (imm offset:2048 buffers),
// bias+ku folded into carried bk. Reduce: 12 DPP + 3 cndmask.
// ---------------------------------------------------------------------------
template <bool USE_KU>
__global__ __attribute__((amdgpu_flat_work_group_size(512, 512),
                          amdgpu_waves_per_eu(2, 2)))
void scan5(const float* __restrict__ Ku,
           const float* __restrict__ inputs,
           const float* __restrict__ Kw,
           const float* __restrict__ h0,
           const float* __restrict__ Hw,
           const float* __restrict__ Hb,
           float* __restrict__ states) {
    const int b   = blockIdx.x;
    const int tid = threadIdx.x;
    const int c   = tid & 7;
    const int jg  = tid >> 3;                    // 0..63
    const int w   = tid >> 6;                    // wave 0..7
    const int r0  = 4 * jg;
    const int row_w = r0 + (c & 3);              // row this lane publishes

    __shared__ __align__(16) char shmem[4096];   // 2 buffers x 2048 B
    char* shm = shmem;

    // permuted chunk positions; p0 is in this wave's own rows [32w,32w+32)
    const int base8 = 8 * w + c;
    const int p0 = base8,            p1 = (base8 +  8) & 63;
    const int p2 = (base8 + 16) & 63, p3 = (base8 + 24) & 63;
    const int p4 = (base8 + 32) & 63, p5 = (base8 + 40) & 63;
    const int p6 = (base8 + 48) & 63, p7 = (base8 + 56) & 63;
    // padded layout: float4 p -> byte 16*(p + p/8)
    int voff0 = 16 * (p0 + (p0 >> 3)), voff1 = 16 * (p1 + (p1 >> 3));
    int voff2 = 16 * (p2 + (p2 >> 3)), voff3 = 16 * (p3 + (p3 >> 3));
    int voff4 = 16 * (p4 + (p4 >> 3)), voff5 = 16 * (p5 + (p5 >> 3));
    int voff6 = 16 * (p6 + (p6 >> 3)), voff7 = 16 * (p7 + (p7 >> 3));
    KEEPF(voff0); KEEPF(voff1); KEEPF(voff2); KEEPF(voff3);
    KEEPF(voff4); KEEPF(voff5); KEEPF(voff6); KEEPF(voff7);

    // ---- weights: rows r0..r0+3, permuted col chunks ----
    DECLROW(A); DECLROW(B); DECLROW(C); DECLROW(D);
    {
        const float* pA = Hw + (size_t)(r0 + 0) * NXc;
        const float* pB = Hw + (size_t)(r0 + 1) * NXc;
        const float* pC = Hw + (size_t)(r0 + 2) * NXc;
        const float* pD = Hw + (size_t)(r0 + 3) * NXc;
        LOADROW(A, pA); LOADROW(B, pB); LOADROW(C, pC); LOADROW(D, pD);
    }
    DECLK8(A); DECLK8(B); DECLK8(C); DECLK8(D);
    const float* uptr = inputs + (size_t)b * Tl * NUc + 8 * c;
    if (!USE_KU) {
        const float* q = Kw + (size_t)r0 * NUc + 8 * c;
        LOADK8(A,q); q += NUc; LOADK8(B,q); q += NUc;
        LOADK8(C,q); q += NUc; LOADK8(D,q);
    }

    const float bias = Hb[row_w];
    const int wbyte  = 4 * (row_w + 4 * (row_w >> 5));   // buf0 write byte

    const float* kup = Ku + (size_t)b * Tl * NXc + NXc + row_w;  // Ku[b,1,row]
    float*       stp = states + (size_t)b * Tl * NXc + NXc + row_w;

    float cA, cB, cC, cD;                        // own-chunk carry
    float bk;                                    // bias + ku for current step
    {
        float h = h0[b * NXc + row_w];
        states[(size_t)b * Tl * NXc + row_w] = h;     // states[b,0,:]
        *(float*)(shm + wbyte) = h;                   // buffer 0
        if (USE_KU) {
            bk = bias + Ku[(size_t)b * Tl * NXc + row_w];
        } else {
            bk = bias;
        }
        asm volatile("s_waitcnt lgkmcnt(0)" ::: "memory");
        float4 Q0_ = *(const float4*)(shm + voff0);   // own rows of h_0
        CARRY4(A, Q0_); CARRY4(B, Q0_); CARRY4(C, Q0_); CARRY4(D, Q0_);
        __syncthreads();
    }

#define STEPBODY(RD, WR) { \
    PINROW(A); PINROW(B); PINROW(C); PINROW(D); \
    if (!USE_KU) { PINK8(A); PINK8(B); PINK8(C); PINK8(D); } \
    float4 Q1 = *(const float4*)(shm + voff1 + (RD)); \
    float4 Q2 = *(const float4*)(shm + voff2 + (RD)); \
    float4 Q3 = *(const float4*)(shm + voff3 + (RD)); \
    float4 Q4 = *(const float4*)(shm + voff4 + (RD)); \
    float4 Q5 = *(const float4*)(shm + voff5 + (RD)); \
    float4 Q6 = *(const float4*)(shm + voff6 + (RD)); \
    float4 Q7 = *(const float4*)(shm + voff7 + (RD)); \
    float kn_ = 0.f; float4 uu0, uu1; \
    if (USE_KU) { kn_ = *kup; kup += NXc; } \
    else { uu0 = *(const float4*)uptr; uu1 = *(const float4*)(uptr + 4); uptr += NUc; } \
    float aA0 = cA, aA1 = 0.f, aB0 = cB, aB1 = 0.f; \
    float aC0 = cC, aC1 = 0.f, aD0 = cD, aD1 = 0.f; \
    FMAROW(A, aA0, aA1); FMAROW(B, aB0, aB1); \
    FMAROW(C, aC0, aC1); FMAROW(D, aD0, aD1); \
    if (!USE_KU) { FMAK8(A,aA0,aA1); FMAK8(B,aB0,aB1); \
                   FMAK8(C,aC0,aC1); FMAK8(D,aD0,aD1); } \
    float rA = aA0 + aA1, rB = aB0 + aB1, rC = aC0 + aC1, rD = aD0 + aD1; \
    rA = dpp_add<0xB1>(rA); rB = dpp_add<0xB1>(rB); \
    rC = dpp_add<0xB1>(rC); rD = dpp_add<0xB1>(rD); \
    rA = dpp_add<0x4E>(rA); rB = dpp_add<0x4E>(rB); \
    rC = dpp_add<0x4E>(rC); rD = dpp_add<0x4E>(rD); \
    rA = dpp_add<0x141>(rA); rB = dpp_add<0x141>(rB); \
    rC = dpp_add<0x141>(rC); rD = dpp_add<0x141>(rD); \
    float x_ = (c & 1) ? rB : rA; \
    float y_ = (c & 1) ? rD : rC; \
    float v_ = (c & 2) ? y_ : x_; \
    float s_ = v_ + bk; \
    float h_ = s_ > 0.f ? s_ : 0.f; \
    *stp = h_; stp += NXc; \
    *(float*)(shm + wbyte + (WR)) = h_; \
    asm volatile("s_waitcnt lgkmcnt(0)" ::: "memory"); \
    float4 Q0_ = *(const float4*)(shm + voff0 + (WR)); \
    CARRY4(A, Q0_); CARRY4(B, Q0_); CARRY4(C, Q0_); CARRY4(D, Q0_); \
    bk = USE_KU ? (bias + kn_) : bias; \
    asm volatile("s_waitcnt lgkmcnt(0)\n\ts_barrier" ::: "memory"); \
}

    for (int tt = 0; tt < (Tl - 2) / 2; ++tt) {   // 2047 pairs = 4094 steps
        STEPBODY(0, 2048);
        STEPBODY(2048, 0);
    }
    STEPBODY(0, 2048);                            // final step t = 4094
#undef STEPBODY
}

// ---------------------------------------------------------------------------
// yest[row, g] = dot(states[row,:], out_w[g,:]) + out_b[g]
// ---------------------------------------------------------------------------
__global__ __launch_bounds__(512, 2) void yest2(const float* __restrict__ states,
                                                const float* __restrict__ ow,
                                                const float* __restrict__ obv,
                                                float* __restrict__ yest) {
    const int tid = threadIdx.x;
    const int c   = tid & 15;
    const int g   = tid >> 4;                    // 0..31

    float y0_,y1_,y2_,y3_,y4_,y5_,y6_,y7_,y8_,y9_,y10_,y11_,y12_,y13_,y14_,y15_;
    {
        const float* wr = ow + (size_t)g * NXc + 16 * c;
        float4 vA = *(const float4*)(wr + 0),  vB = *(const float4*)(wr + 4);
        float4 vC = *(const float4*)(wr + 8),  vD = *(const float4*)(wr + 12);
        y0_=vA.x; y1_=vA.y; y2_ =vA.z; y3_ =vA.w;
        y4_=vB.x; y5_=vB.y; y6_ =vB.z; y7_ =vB.w;
        y8_=vC.x; y9_=vC.y; y10_=vC.z; y11_=vC.w;
        y12_=vD.x;y13_=vD.y;y14_=vD.z; y15_=vD.w;
        KEEPF(y0_); KEEPF(y1_); KEEPF(y2_);  KEEPF(y3_);
        KEEPF(y4_); KEEPF(y5_); KEEPF(y6_);  KEEPF(y7_);
        KEEPF(y8_); KEEPF(y9_); KEEPF(y10_); KEEPF(y11_);
        KEEPF(y12_);KEEPF(y13_);KEEPF(y14_); KEEPF(y15_);
    }
    const float ob = obv[g];

    const int row0 = blockIdx.x * 128;
    for (int r = 0; r < 128; r += 2) {
        const float* s0p = states + (size_t)(row0 + r) * NXc + 16 * c;
        const float* s1p = s0p + NXc;
        float4 A0 = *(const float4*)(s0p + 0), A1 = *(const float4*)(s0p + 4);
        float4 A2 = *(const float4*)(s0p + 8), A3 = *(const float4*)(s0p + 12);
        float4 B0 = *(const float4*)(s1p + 0), B1 = *(const float4*)(s1p + 4);
        float4 B2 = *(const float4*)(s1p + 8), B3 = *(const float4*)(s1p + 12);
        float acc0 = y0_*A0.x + y1_*A0.y + y2_*A0.z + y3_*A0.w
                   + y4_*A1.x + y5_*A1.y + y6_*A1.z + y7_*A1.w
                   + y8_*A2.x + y9_*A2.y + y10_*A2.z + y11_*A2.w
                   + y12_*A3.x + y13_*A3.y + y14_*A3.z + y15_*A3.w;
        float acc1 = y0_*B0.x + y1_*B0.y + y2_*B0.z + y3_*B0.w
                   + y4_*B1.x + y5_*B1.y + y6_*B1.z + y7_*B1.w
                   + y8_*B2.x + y9_*B2.y + y10_*B2.z + y11_*B2.w
                   + y12_*B3.x + y13_*B3.y + y14_*B3.z + y15_*B3.w;
        acc0 = row_reduce16(acc0);
        acc1 = row_reduce16(acc1);
        if (c == 0) {
            yest[(size_t)(row0 + r)     * NYc + g] = acc0 + ob;
            yest[(size_t)(row0 + r + 1) * NYc + g] = acc1 + ob;
        }
    }
}

// ---------------------------------------------------------------------------
extern "C" void kernel_launch(void* const* d_in, const int* in_sizes, int n_in,
                              void* d_out, int out_size, void* d_ws, size_t ws_size,
                              hipStream_t stream) {
    const float* inputs = (const float*)d_in[0];   // [B,T,NU]
    const float* h0     = (const float*)d_in[1];   // [B,NX]
    const float* Hw     = (const float*)d_in[2];   // [NX,NX]
    const float* Hb     = (const float*)d_in[3];   // [NX]
    const float* Kw     = (const float*)d_in[4];   // [NX,NU]
    // d_in[5] = E_inv: identity; relu(x) @ I == relu(x) exactly.
    const float* ow     = (const float*)d_in[6];   // [NY,NX]
    const float* ob     = (const float*)d_in[7];   // [NY]

    float* yest   = (float*)d_out;                              // [B,T,NY]
    float* states = (float*)d_out + (size_t)Bsz * Tl * NYc;     // [B,T,NX]

    const size_t ku_bytes = (size_t)Bsz * Tl * NXc * sizeof(float);  // 64 MB
    const int    nrows    = Bsz * Tl;

    if (ws_size >= ku_bytes) {
        float* Ku = (float*)d_ws;
        ku_kernel<<<dim3(nrows / 64), dim3(256), 0, stream>>>(inputs, Kw, Ku);
        scan5<true><<<dim3(Bsz), dim3(512), 0, stream>>>(Ku, inputs, Kw, h0, Hw, Hb, states);
    } else {
        scan5<false><<<dim3(Bsz), dim3(512), 0, stream>>>(nullptr, inputs, Kw, h0, Hw, Hb, states);
    }
    yest2<<<dim3(nrows / 128), dim3(512), 0, stream>>>(states, ow, ob, yest);
}

// Round 8
// 1985.032 us; speedup vs baseline: 1.2411x; 1.2411x over previous
//
#include <hip/hip_runtime.h>

#define Bsz 16
#define Tl  4096
#define NUc 64
#define NXc 256
#define NYc 32

// ---------------------------------------------------------------------------
// DPP cross-lane reductions (pure VALU, no LDS pipe).
// ---------------------------------------------------------------------------
template <int CTRL>
__device__ __forceinline__ float dpp_add(float x) {
    int y = __builtin_amdgcn_update_dpp(0, __float_as_int(x), CTRL, 0xf, 0xf, true);
    return x + __int_as_float(y);
}
// sum over an aligned group of 8 contiguous lanes (all 8 get the sum)
__device__ __forceinline__ float reduce8(float x) {
    x = dpp_add<0xB1>(x);    // quad_perm xor1
    x = dpp_add<0x4E>(x);    // quad_perm xor2
    x = dpp_add<0x141>(x);   // row_half_mirror (pairs the two quads)
    return x;
}
__device__ __forceinline__ float row_reduce16(float x) {
    x = dpp_add<0x128>(x);   // row_ror:8
    x = dpp_add<0x124>(x);   // row_ror:4
    x = dpp_add<0x4E>(x);
    x = dpp_add<0xB1>(x);
    return x;
}

// barrier WITHOUT the vmcnt(0) drain: LDS visibility only.
__device__ __forceinline__ void fast_barrier() {
    asm volatile("s_waitcnt lgkmcnt(0)\n\ts_barrier" ::: "memory");
}

// keep-alive on a NAMED scalar
#define KEEPF(x) asm volatile("" : "+v"(x))

// ---------------- named-scalar weight macros (16 floats) -------------------
#define DECLW(T,P) \
    float W##T##P##_0,W##T##P##_1,W##T##P##_2,W##T##P##_3,W##T##P##_4,W##T##P##_5,W##T##P##_6,W##T##P##_7, \
          W##T##P##_8,W##T##P##_9,W##T##P##_10,W##T##P##_11,W##T##P##_12,W##T##P##_13,W##T##P##_14,W##T##P##_15
#define LOADW(T,P,RP) { \
    const float* wr_ = (RP) + 16*P; \
    float4 a_=*(const float4*)(wr_+0), b_=*(const float4*)(wr_+4); \
    float4 c_=*(const float4*)(wr_+8), d_=*(const float4*)(wr_+12); \
    W##T##P##_0 =a_.x; W##T##P##_1 =a_.y; W##T##P##_2 =a_.z; W##T##P##_3 =a_.w; \
    W##T##P##_4 =b_.x; W##T##P##_5 =b_.y; W##T##P##_6 =b_.z; W##T##P##_7 =b_.w; \
    W##T##P##_8 =c_.x; W##T##P##_9 =c_.y; W##T##P##_10=c_.z; W##T##P##_11=c_.w; \
    W##T##P##_12=d_.x; W##T##P##_13=d_.y; W##T##P##_14=d_.z; W##T##P##_15=d_.w; }
#define PINW(T,P) \
    KEEPF(W##T##P##_0);  KEEPF(W##T##P##_1);  KEEPF(W##T##P##_2);  KEEPF(W##T##P##_3);  \
    KEEPF(W##T##P##_4);  KEEPF(W##T##P##_5);  KEEPF(W##T##P##_6);  KEEPF(W##T##P##_7);  \
    KEEPF(W##T##P##_8);  KEEPF(W##T##P##_9);  KEEPF(W##T##P##_10); KEEPF(W##T##P##_11); \
    KEEPF(W##T##P##_12); KEEPF(W##T##P##_13); KEEPF(W##T##P##_14); KEEPF(W##T##P##_15)

// 4 FMAs of row T, 16-chunk P, sub-indices A..D against float4 Q
#define FMAQn(T,P,IA,IB,IC,ID,Q) \
    a##T##0 = fmaf(W##T##P##_##IA, (Q).x, a##T##0); \
    a##T##1 = fmaf(W##T##P##_##IB, (Q).y, a##T##1); \
    a##T##0 = fmaf(W##T##P##_##IC, (Q).z, a##T##0); \
    a##T##1 = fmaf(W##T##P##_##ID, (Q).w, a##T##1)
// all 32 cols of row T against Q0..Q7
#define ROWFMA(T) \
    FMAQn(T,0, 0, 1, 2, 3, Q0); FMAQn(T,0, 4, 5, 6, 7, Q1); \
    FMAQn(T,0, 8, 9,10,11, Q2); FMAQn(T,0,12,13,14,15, Q3); \
    FMAQn(T,1, 0, 1, 2, 3, Q4); FMAQn(T,1, 4, 5, 6, 7, Q5); \
    FMAQn(T,1, 8, 9,10,11, Q6); FMAQn(T,1,12,13,14,15, Q7)

// inline-K fallback: 8 u-weights per row
#define DECLK8(T) float kk##T##_0,kk##T##_1,kk##T##_2,kk##T##_3,kk##T##_4,kk##T##_5,kk##T##_6,kk##T##_7
#define LOADK8(T,RP) { \
    float4 a_=*(const float4*)(RP), b_=*(const float4*)((RP)+4); \
    kk##T##_0=a_.x; kk##T##_1=a_.y; kk##T##_2=a_.z; kk##T##_3=a_.w; \
    kk##T##_4=b_.x; kk##T##_5=b_.y; kk##T##_6=b_.z; kk##T##_7=b_.w; }
#define PINK8(T) \
    KEEPF(kk##T##_0); KEEPF(kk##T##_1); KEEPF(kk##T##_2); KEEPF(kk##T##_3); \
    KEEPF(kk##T##_4); KEEPF(kk##T##_5); KEEPF(kk##T##_6); KEEPF(kk##T##_7)
#define FMAK8(T) \
    a##T##0=fmaf(kk##T##_0,uu0.x,a##T##0); a##T##1=fmaf(kk##T##_1,uu0.y,a##T##1); \
    a##T##0=fmaf(kk##T##_2,uu0.z,a##T##0); a##T##1=fmaf(kk##T##_3,uu0.w,a##T##1); \
    a##T##0=fmaf(kk##T##_4,uu1.x,a##T##0); a##T##1=fmaf(kk##T##_5,uu1.y,a##T##1); \
    a##T##0=fmaf(kk##T##_6,uu1.z,a##T##0); a##T##1=fmaf(kk##T##_7,uu1.w,a##T##1)

// ---------------------------------------------------------------------------
// Ku[row, x] = sum_u inputs[row, u] * K_w[x, u]   (parallel, full GPU)
// ---------------------------------------------------------------------------
#define KDECL4(Q)  float k##Q##_0, k##Q##_1, k##Q##_2, k##Q##_3
#define KLOAD4(Q) { float4 v_ = *(const float4*)(wr_ + 4*Q); \
    k##Q##_0 = v_.x; k##Q##_1 = v_.y; k##Q##_2 = v_.z; k##Q##_3 = v_.w; }
#define KPIN4(Q)   KEEPF(k##Q##_0); KEEPF(k##Q##_1); KEEPF(k##Q##_2); KEEPF(k##Q##_3)
#define KACC4(Q, U) { \
    s0_ = fmaf(k##Q##_0, (U).x, s0_); s1_ = fmaf(k##Q##_1, (U).y, s1_); \
    s0_ = fmaf(k##Q##_2, (U).z, s0_); s1_ = fmaf(k##Q##_3, (U).w, s1_); }

__global__ __launch_bounds__(256) void ku_kernel(const float* __restrict__ inputs,
                                                 const float* __restrict__ Kw,
                                                 float* __restrict__ Ku) {
    const int x    = threadIdx.x;
    const int row0 = blockIdx.x * 64;

    const float* wr_ = Kw + (size_t)x * NUc;
    KDECL4(0);  KDECL4(1);  KDECL4(2);  KDECL4(3);
    KDECL4(4);  KDECL4(5);  KDECL4(6);  KDECL4(7);
    KDECL4(8);  KDECL4(9);  KDECL4(10); KDECL4(11);
    KDECL4(12); KDECL4(13); KDECL4(14); KDECL4(15);
    KLOAD4(0);  KLOAD4(1);  KLOAD4(2);  KLOAD4(3);
    KLOAD4(4);  KLOAD4(5);  KLOAD4(6);  KLOAD4(7);
    KLOAD4(8);  KLOAD4(9);  KLOAD4(10); KLOAD4(11);
    KLOAD4(12); KLOAD4(13); KLOAD4(14); KLOAD4(15);
    KPIN4(0);  KPIN4(1);  KPIN4(2);  KPIN4(3);
    KPIN4(4);  KPIN4(5);  KPIN4(6);  KPIN4(7);
    KPIN4(8);  KPIN4(9);  KPIN4(10); KPIN4(11);
    KPIN4(12); KPIN4(13); KPIN4(14); KPIN4(15);

    __shared__ float sin_[64 * NUc];     // 16 KB
    {
        const float* src = inputs + (size_t)row0 * NUc;
        #pragma unroll
        for (int i = 0; i < 16; ++i)
            sin_[threadIdx.x + i * 256] = src[threadIdx.x + i * 256];
    }
    __syncthreads();

    for (int r = 0; r < 64; ++r) {
        const float4* hp = (const float4*)(&sin_[r * NUc]);  // wave-uniform
        float s0_ = 0.f, s1_ = 0.f;
        KACC4(0,  hp[0]);  KACC4(1,  hp[1]);  KACC4(2,  hp[2]);  KACC4(3,  hp[3]);
        KACC4(4,  hp[4]);  KACC4(5,  hp[5]);  KACC4(6,  hp[6]);  KACC4(7,  hp[7]);
        KACC4(8,  hp[8]);  KACC4(9,  hp[9]);  KACC4(10, hp[10]); KACC4(11, hp[11]);
        KACC4(12, hp[12]); KACC4(13, hp[13]); KACC4(14, hp[14]); KACC4(15, hp[15]);
        Ku[(size_t)(row0 + r) * NXc + x] = s0_ + s1_;
    }
}

// ---------------------------------------------------------------------------
// Scan v6 = proven scan4 structure + micro-trims:
//   * unroll x2, immediate LDS buffer offsets (no per-step offset xors)
//   * bk = bias + ku folded in the prefetch shadow (1 carried scalar)
//   * phase-split: rows A,B FMA -> reduce A,B while rows C,D FMA issue
// lane: c = tid&7 covers cols [32c,32c+32); jg = tid>>3 owns rows 4jg..4jg+3.
// 128 weight scalars resident (re-pinned each iter). h double-buffered in
// padded LDS (slot(f4)=f4+f4/8): 8 ds_read_b128/lane at immediate offsets,
// bank-quads (c+q)&7 -> conflict-free. ONE lgkmcnt-only barrier per step.
// ---------------------------------------------------------------------------
template <bool USE_KU>
__global__ __attribute__((amdgpu_flat_work_group_size(512, 512),
                          amdgpu_waves_per_eu(2, 2)))
void scan6(const float* __restrict__ Ku,
           const float* __restrict__ inputs,
           const float* __restrict__ Kw,
           const float* __restrict__ h0,
           const float* __restrict__ Hw,
           const float* __restrict__ Hb,
           float* __restrict__ states) {
    const int b   = blockIdx.x;
    const int tid = threadIdx.x;
    const int c   = tid & 7;
    const int jg  = tid >> 3;                    // 0..63
    const int r0  = 4 * jg;
    const int row_w = r0 + (c & 3);              // row this lane publishes

    __shared__ __align__(16) char shmem[4096];   // 2 buffers x 2048 B
    char* shm = shmem;
    float* shf = (float*)shmem;

    // ---- recurrent weights: rows r0..r0+3, cols [32c,32c+32) = 128 scalars
    DECLW(A,0); DECLW(A,1); DECLW(B,0); DECLW(B,1);
    DECLW(C,0); DECLW(C,1); DECLW(D,0); DECLW(D,1);
    {
        const float* p = Hw + (size_t)r0 * NXc + 32 * c;
        LOADW(A,0,p); LOADW(A,1,p);  p += NXc;
        LOADW(B,0,p); LOADW(B,1,p);  p += NXc;
        LOADW(C,0,p); LOADW(C,1,p);  p += NXc;
        LOADW(D,0,p); LOADW(D,1,p);
    }
    // inline-K fallback weights: rows r0..r0+3, u-cols [8c,8c+8)
    DECLK8(A); DECLK8(B); DECLK8(C); DECLK8(D);
    const float* uptr = inputs + (size_t)b * Tl * NUc + 8 * c;   // u row 0
    if (!USE_KU) {
        const float* q = Kw + (size_t)r0 * NUc + 8 * c;
        LOADK8(A,q); q += NUc; LOADK8(B,q); q += NUc;
        LOADK8(C,q); q += NUc; LOADK8(D,q);
    }

    const float bias = Hb[row_w];

    // padded layout: float4 f4 -> slot f4 + f4/8 (72 f4 = 1152 B per buffer)
    const int wbyte  = 4 * (row_w + 4 * (row_w >> 5));   // write byte in buf0
    const int rbase  = 144 * c;                          // read base in buf0

    const float* kup = Ku + (size_t)b * Tl * NXc + NXc + row_w;  // Ku[b,1,row_w]
    float*       stp = states + (size_t)b * Tl * NXc + NXc + row_w;

    float bk;                                    // bias (+ku) for current step
    {
        float h = h0[b * NXc + row_w];
        states[(size_t)b * Tl * NXc + row_w] = h;     // states[b,0,:]
        shf[wbyte >> 2] = h;                          // buffer 0
        bk = USE_KU ? (bias + Ku[(size_t)b * Tl * NXc + row_w]) : bias;
        __syncthreads();
    }

#define STEPBODY(RD, WR) { \
    PINW(A,0); PINW(A,1); PINW(B,0); PINW(B,1); \
    PINW(C,0); PINW(C,1); PINW(D,0); PINW(D,1); \
    if (!USE_KU) { PINK8(A); PINK8(B); PINK8(C); PINK8(D); } \
    const char* rb = shm + (rbase + (RD)); \
    float4 Q0 = *(const float4*)(rb +   0); \
    float4 Q1 = *(const float4*)(rb +  16); \
    float4 Q2 = *(const float4*)(rb +  32); \
    float4 Q3 = *(const float4*)(rb +  48); \
    float4 Q4 = *(const float4*)(rb +  64); \
    float4 Q5 = *(const float4*)(rb +  80); \
    float4 Q6 = *(const float4*)(rb +  96); \
    float4 Q7 = *(const float4*)(rb + 112); \
    float kn_ = 0.f; float4 uu0, uu1; \
    if (USE_KU) { kn_ = *kup; kup += NXc; } \
    else { uu0 = *(const float4*)uptr; uu1 = *(const float4*)(uptr + 4); uptr += NUc; } \
    float aA0=0.f,aA1=0.f,aB0=0.f,aB1=0.f,aC0=0.f,aC1=0.f,aD0=0.f,aD1=0.f; \
    if (!USE_KU) { FMAK8(A); FMAK8(B); FMAK8(C); FMAK8(D); } \
    ROWFMA(A); ROWFMA(B); \
    float rA = reduce8(aA0 + aA1); \
    float rB = reduce8(aB0 + aB1); \
    ROWFMA(C); ROWFMA(D); \
    float rC = reduce8(aC0 + aC1); \
    float rD = reduce8(aD0 + aD1); \
    float x_ = (c & 1) ? rB : rA; \
    float y_ = (c & 1) ? rD : rC; \
    float v_ = (c & 2) ? y_ : x_; \
    float s_ = v_ + bk; \
    float h_ = s_ > 0.f ? s_ : 0.f; \
    *stp = h_; stp += NXc; \
    *(float*)(shm + (wbyte + (WR))) = h_; \
    bk = USE_KU ? (bias + kn_) : bias; \
    fast_barrier(); \
}

    for (int tt = 0; tt < (Tl - 2) / 2; ++tt) {   // 2047 pairs = 4094 steps
        STEPBODY(0, 2048);
        STEPBODY(2048, 0);
    }
    STEPBODY(0, 2048);                            // final step -> 4095 total
#undef STEPBODY
}

// ---------------------------------------------------------------------------
// yest[row, g] = dot(states[row,:], out_w[g,:]) + out_b[g]
// ---------------------------------------------------------------------------
__global__ __launch_bounds__(512, 2) void yest2(const float* __restrict__ states,
                                                const float* __restrict__ ow,
                                                const float* __restrict__ obv,
                                                float* __restrict__ yest) {
    const int tid = threadIdx.x;
    const int c   = tid & 15;
    const int g   = tid >> 4;                    // 0..31

    float y0_,y1_,y2_,y3_,y4_,y5_,y6_,y7_,y8_,y9_,y10_,y11_,y12_,y13_,y14_,y15_;
    {
        const float* wr = ow + (size_t)g * NXc + 16 * c;
        float4 vA = *(const float4*)(wr + 0),  vB = *(const float4*)(wr + 4);
        float4 vC = *(const float4*)(wr + 8),  vD = *(const float4*)(wr + 12);
        y0_=vA.x; y1_=vA.y; y2_ =vA.z; y3_ =vA.w;
        y4_=vB.x; y5_=vB.y; y6_ =vB.z; y7_ =vB.w;
        y8_=vC.x; y9_=vC.y; y10_=vC.z; y11_=vC.w;
        y12_=vD.x;y13_=vD.y;y14_=vD.z; y15_=vD.w;
        KEEPF(y0_); KEEPF(y1_); KEEPF(y2_);  KEEPF(y3_);
        KEEPF(y4_); KEEPF(y5_); KEEPF(y6_);  KEEPF(y7_);
        KEEPF(y8_); KEEPF(y9_); KEEPF(y10_); KEEPF(y11_);
        KEEPF(y12_);KEEPF(y13_);KEEPF(y14_); KEEPF(y15_);
    }
    const float ob = obv[g];

    const int row0 = blockIdx.x * 128;
    for (int r = 0; r < 128; r += 2) {
        const float* s0p = states + (size_t)(row0 + r) * NXc + 16 * c;
        const float* s1p = s0p + NXc;
        float4 A0 = *(const float4*)(s0p + 0), A1 = *(const float4*)(s0p + 4);
        float4 A2 = *(const float4*)(s0p + 8), A3 = *(const float4*)(s0p + 12);
        float4 B0 = *(const float4*)(s1p + 0), B1 = *(const float4*)(s1p + 4);
        float4 B2 = *(const float4*)(s1p + 8), B3 = *(const float4*)(s1p + 12);
        float acc0 = y0_*A0.x + y1_*A0.y + y2_*A0.z + y3_*A0.w
                   + y4_*A1.x + y5_*A1.y + y6_*A1.z + y7_*A1.w
                   + y8_*A2.x + y9_*A2.y + y10_*A2.z + y11_*A2.w
                   + y12_*A3.x + y13_*A3.y + y14_*A3.z + y15_*A3.w;
        float acc1 = y0_*B0.x + y1_*B0.y + y2_*B0.z + y3_*B0.w
                   + y4_*B1.x + y5_*B1.y + y6_*B1.z + y7_*B1.w
                   + y8_*B2.x + y9_*B2.y + y10_*B2.z + y11_*B2.w
                   + y12_*B3.x + y13_*B3.y + y14_*B3.z + y15_*B3.w;
        acc0 = row_reduce16(acc0);
        acc1 = row_reduce16(acc1);
        if (c == 0) {
            yest[(size_t)(row0 + r)     * NYc + g] = acc0 + ob;
            yest[(size_t)(row0 + r + 1) * NYc + g] = acc1 + ob;
        }
    }
}

// ---------------------------------------------------------------------------
extern "C" void kernel_launch(void* const* d_in, const int* in_sizes, int n_in,
                              void* d_out, int out_size, void* d_ws, size_t ws_size,
                              hipStream_t stream) {
    const float* inputs = (const float*)d_in[0];   // [B,T,NU]
    const float* h0     = (const float*)d_in[1];   // [B,NX]
    const float* Hw     = (const float*)d_in[2];   // [NX,NX]
    const float* Hb     = (const float*)d_in[3];   // [NX]
    const float* Kw     = (const float*)d_in[4];   // [NX,NU]
    // d_in[5] = E_inv: identity; relu(x) @ I == relu(x) exactly.
    const float* ow     = (const float*)d_in[6];   // [NY,NX]
    const float* ob     = (const float*)d_in[7];   // [NY]

    float* yest   = (float*)d_out;                              // [B,T,NY]
    float* states = (float*)d_out + (size_t)Bsz * Tl * NYc;     // [B,T,NX]

    const size_t ku_bytes = (size_t)Bsz * Tl * NXc * sizeof(float);  // 64 MB
    const int    nrows    = Bsz * Tl;

    if (ws_size >= ku_bytes) {
        float* Ku = (float*)d_ws;
        ku_kernel<<<dim3(nrows / 64), dim3(256), 0, stream>>>(inputs, Kw, Ku);
        scan6<true><<<dim3(Bsz), dim3(512), 0, stream>>>(Ku, inputs, Kw, h0, Hw, Hb, states);
    } else {
        scan6<false><<<dim3(Bsz), dim3(512), 0, stream>>>(nullptr, inputs, Kw, h0, Hw, Hb, states);
    }
    yest2<<<dim3(nrows / 128), dim3(512), 0, stream>>>(states, ow, ob, yest);
}

// Round 9
// 1946.579 us; speedup vs baseline: 1.2656x; 1.0198x over previous
//
#include <hip/hip_runtime.h>

#define Bsz 16
#define Tl  4096
#define NUc 64
#define NXc 256
#define NYc 32

// ---------------------------------------------------------------------------
// DPP cross-lane reductions.
// ---------------------------------------------------------------------------
template <int CTRL>
__device__ __forceinline__ float dpp_add(float x) {
    int y = __builtin_amdgcn_update_dpp(0, __float_as_int(x), CTRL, 0xf, 0xf, true);
    return x + __int_as_float(y);
}
__device__ __forceinline__ float row_reduce16(float x) {
    x = dpp_add<0x128>(x);   // row_ror:8
    x = dpp_add<0x124>(x);   // row_ror:4
    x = dpp_add<0x4E>(x);    // quad_perm xor2
    x = dpp_add<0xB1>(x);    // quad_perm xor1
    return x;
}

// 4 parallel 8-lane reductions, fused v_add_f32_dpp, hazard-safe interleave
// (every dpp source was written >= 3 instructions earlier).
__device__ __forceinline__ void red8x4(float sA, float sB, float sC, float sD,
                                       float& rA, float& rB, float& rC, float& rD) {
    asm("v_add_f32_dpp %0, %4, %4 quad_perm:[1,0,3,2] row_mask:0xf bank_mask:0xf\n\t"
        "v_add_f32_dpp %1, %5, %5 quad_perm:[1,0,3,2] row_mask:0xf bank_mask:0xf\n\t"
        "v_add_f32_dpp %2, %6, %6 quad_perm:[1,0,3,2] row_mask:0xf bank_mask:0xf\n\t"
        "v_add_f32_dpp %3, %7, %7 quad_perm:[1,0,3,2] row_mask:0xf bank_mask:0xf\n\t"
        "v_add_f32_dpp %0, %0, %0 quad_perm:[2,3,0,1] row_mask:0xf bank_mask:0xf\n\t"
        "v_add_f32_dpp %1, %1, %1 quad_perm:[2,3,0,1] row_mask:0xf bank_mask:0xf\n\t"
        "v_add_f32_dpp %2, %2, %2 quad_perm:[2,3,0,1] row_mask:0xf bank_mask:0xf\n\t"
        "v_add_f32_dpp %3, %3, %3 quad_perm:[2,3,0,1] row_mask:0xf bank_mask:0xf\n\t"
        "v_add_f32_dpp %0, %0, %0 row_half_mirror row_mask:0xf bank_mask:0xf\n\t"
        "v_add_f32_dpp %1, %1, %1 row_half_mirror row_mask:0xf bank_mask:0xf\n\t"
        "v_add_f32_dpp %2, %2, %2 row_half_mirror row_mask:0xf bank_mask:0xf\n\t"
        "v_add_f32_dpp %3, %3, %3 row_half_mirror row_mask:0xf bank_mask:0xf"
        : "=&v"(rA), "=&v"(rB), "=&v"(rC), "=&v"(rD)
        : "v"(sA), "v"(sB), "v"(sC), "v"(sD));
}

// keep-alive on a NAMED scalar
#define KEEPF(x) asm volatile("" : "+v"(x))

// ---------------- per-chunk weight macros (4 floats each) ------------------
#define DECLC(T,J) float W##T##J##_0, W##T##J##_1, W##T##J##_2, W##T##J##_3
#define LOADC(T,J,P) { float4 v_ = *(const float4*)(P); \
    W##T##J##_0=v_.x; W##T##J##_1=v_.y; W##T##J##_2=v_.z; W##T##J##_3=v_.w; }
#define PINC(T,J) KEEPF(W##T##J##_0); KEEPF(W##T##J##_1); \
                  KEEPF(W##T##J##_2); KEEPF(W##T##J##_3)
#define FMAC4(T,J,Q) \
    a##T##0 = fmaf(W##T##J##_0, (Q).x, a##T##0); \
    a##T##1 = fmaf(W##T##J##_1, (Q).y, a##T##1); \
    a##T##0 = fmaf(W##T##J##_2, (Q).z, a##T##0); \
    a##T##1 = fmaf(W##T##J##_3, (Q).w, a##T##1)

#define DECL8(T) DECLC(T,0); DECLC(T,1); DECLC(T,2); DECLC(T,3); \
                 DECLC(T,4); DECLC(T,5); DECLC(T,6); DECLC(T,7)
#define LOAD8(T,RP) \
    LOADC(T,0,(RP)+4*q0); LOADC(T,1,(RP)+4*q1); LOADC(T,2,(RP)+4*q2); \
    LOADC(T,3,(RP)+4*q3); LOADC(T,4,(RP)+4*q4); LOADC(T,5,(RP)+4*q5); \
    LOADC(T,6,(RP)+4*q6); LOADC(T,7,(RP)+4*q7)
#define PIN8(T) PINC(T,0); PINC(T,1); PINC(T,2); PINC(T,3); \
                PINC(T,4); PINC(T,5); PINC(T,6); PINC(T,7)
#define CHUNKF(J,Q) FMAC4(A,J,Q); FMAC4(B,J,Q); FMAC4(C,J,Q); FMAC4(D,J,Q)

// inline-K fallback: 8 u-weights per row
#define DECLK8(T) float kk##T##_0,kk##T##_1,kk##T##_2,kk##T##_3,kk##T##_4,kk##T##_5,kk##T##_6,kk##T##_7
#define LOADK8(T,RP) { \
    float4 a_=*(const float4*)(RP), b_=*(const float4*)((RP)+4); \
    kk##T##_0=a_.x; kk##T##_1=a_.y; kk##T##_2=a_.z; kk##T##_3=a_.w; \
    kk##T##_4=b_.x; kk##T##_5=b_.y; kk##T##_6=b_.z; kk##T##_7=b_.w; }
#define PINK8(T) \
    KEEPF(kk##T##_0); KEEPF(kk##T##_1); KEEPF(kk##T##_2); KEEPF(kk##T##_3); \
    KEEPF(kk##T##_4); KEEPF(kk##T##_5); KEEPF(kk##T##_6); KEEPF(kk##T##_7)
#define FMAK8(T) \
    a##T##0=fmaf(kk##T##_0,uu0.x,a##T##0); a##T##1=fmaf(kk##T##_1,uu0.y,a##T##1); \
    a##T##0=fmaf(kk##T##_2,uu0.z,a##T##0); a##T##1=fmaf(kk##T##_3,uu0.w,a##T##1); \
    a##T##0=fmaf(kk##T##_4,uu1.x,a##T##0); a##T##1=fmaf(kk##T##_5,uu1.y,a##T##1); \
    a##T##0=fmaf(kk##T##_6,uu1.z,a##T##0); a##T##1=fmaf(kk##T##_7,uu1.w,a##T##1)

// ---------------------------------------------------------------------------
// Ku[row, x] = sum_u inputs[row, u] * K_w[x, u]   (parallel, full GPU)
// ---------------------------------------------------------------------------
#define KDECL4(Q)  float k##Q##_0, k##Q##_1, k##Q##_2, k##Q##_3
#define KLOAD4(Q) { float4 v_ = *(const float4*)(wr_ + 4*Q); \
    k##Q##_0 = v_.x; k##Q##_1 = v_.y; k##Q##_2 = v_.z; k##Q##_3 = v_.w; }
#define KPIN4(Q)   KEEPF(k##Q##_0); KEEPF(k##Q##_1); KEEPF(k##Q##_2); KEEPF(k##Q##_3)
#define KACC4(Q, U) { \
    s0_ = fmaf(k##Q##_0, (U).x, s0_); s1_ = fmaf(k##Q##_1, (U).y, s1_); \
    s0_ = fmaf(k##Q##_2, (U).z, s0_); s1_ = fmaf(k##Q##_3, (U).w, s1_); }

__global__ __launch_bounds__(256) void ku_kernel(const float* __restrict__ inputs,
                                                 const float* __restrict__ Kw,
                                                 float* __restrict__ Ku) {
    const int x    = threadIdx.x;
    const int row0 = blockIdx.x * 64;

    const float* wr_ = Kw + (size_t)x * NUc;
    KDECL4(0);  KDECL4(1);  KDECL4(2);  KDECL4(3);
    KDECL4(4);  KDECL4(5);  KDECL4(6);  KDECL4(7);
    KDECL4(8);  KDECL4(9);  KDECL4(10); KDECL4(11);
    KDECL4(12); KDECL4(13); KDECL4(14); KDECL4(15);
    KLOAD4(0);  KLOAD4(1);  KLOAD4(2);  KLOAD4(3);
    KLOAD4(4);  KLOAD4(5);  KLOAD4(6);  KLOAD4(7);
    KLOAD4(8);  KLOAD4(9);  KLOAD4(10); KLOAD4(11);
    KLOAD4(12); KLOAD4(13); KLOAD4(14); KLOAD4(15);
    KPIN4(0);  KPIN4(1);  KPIN4(2);  KPIN4(3);
    KPIN4(4);  KPIN4(5);  KPIN4(6);  KPIN4(7);
    KPIN4(8);  KPIN4(9);  KPIN4(10); KPIN4(11);
    KPIN4(12); KPIN4(13); KPIN4(14); KPIN4(15);

    __shared__ float sin_[64 * NUc];     // 16 KB
    {
        const float* src = inputs + (size_t)row0 * NUc;
        #pragma unroll
        for (int i = 0; i < 16; ++i)
            sin_[threadIdx.x + i * 256] = src[threadIdx.x + i * 256];
    }
    __syncthreads();

    for (int r = 0; r < 64; ++r) {
        const float4* hp = (const float4*)(&sin_[r * NUc]);  // wave-uniform
        float s0_ = 0.f, s1_ = 0.f;
        KACC4(0,  hp[0]);  KACC4(1,  hp[1]);  KACC4(2,  hp[2]);  KACC4(3,  hp[3]);
        KACC4(4,  hp[4]);  KACC4(5,  hp[5]);  KACC4(6,  hp[6]);  KACC4(7,  hp[7]);
        KACC4(8,  hp[8]);  KACC4(9,  hp[9]);  KACC4(10, hp[10]); KACC4(11, hp[11]);
        KACC4(12, hp[12]); KACC4(13, hp[13]); KACC4(14, hp[14]); KACC4(15, hp[15]);
        Ku[(size_t)(row0 + r) * NXc + x] = s0_ + s1_;
    }
}

// ---------------------------------------------------------------------------
// Scan v7: scan6 + permuted DOUBLE-IMAGE LDS layout + carried Q0.
// lane (c=tid&7, jg=tid>>3, w=tid>>6): rows 4jg..4jg+3; 32 cols as 8 float4
// chunks at positions p_j=(8w+c+8j)&63 — p_0 is in the wave's OWN rows.
// h image stored twice (lanes c<4 -> image0, c>=4 -> image1; these lanes held
// duplicate values anyway), so slot(p0+8j)=slot(p0)+9j with NO wrap: one base
// VGPR + immediate offsets 144j. End of body: ds_write -> issue next-Q0
// ds_read -> s_waitcnt lgkmcnt(1) (write drained, READ STAYS IN FLIGHT) ->
// s_barrier. Post-barrier FMAs start on carried Q0 immediately.
// Padded slot(p)=p+p/8: image 72 f4 = 1152 B; buffer 2304 B; 2 buffers.
// ---------------------------------------------------------------------------
template <bool USE_KU>
__global__ __attribute__((amdgpu_flat_work_group_size(512, 512),
                          amdgpu_waves_per_eu(2, 2)))
void scan7(const float* __restrict__ Ku,
           const float* __restrict__ inputs,
           const float* __restrict__ Kw,
           const float* __restrict__ h0,
           const float* __restrict__ Hw,
           const float* __restrict__ Hb,
           float* __restrict__ states) {
    const int b   = blockIdx.x;
    const int tid = threadIdx.x;
    const int c   = tid & 7;
    const int jg  = tid >> 3;                    // 0..63
    const int w   = tid >> 6;                    // wave 0..7
    const int r0  = 4 * jg;
    const int row_w = r0 + (c & 3);              // row this lane publishes

    __shared__ __align__(16) char shmem[4608];   // 2 buffers x 2 images x 1152
    char* shm = shmem;

    // chunk positions and addressing
    const int p0   = 8 * w + c;                  // own-wave float4 (no mod)
    const int q0 = p0,               q1 = (p0 +  8) & 63;
    const int q2 = (p0 + 16) & 63,   q3 = (p0 + 24) & 63;
    const int q4 = (p0 + 32) & 63,   q5 = (p0 + 40) & 63;
    const int q6 = (p0 + 48) & 63,   q7 = (p0 + 56) & 63;
    const int rdv   = 16 * (p0 + (p0 >> 3));     // read base byte (buffer 0)
    const int wslot = row_w + 4 * (row_w >> 5);  // padded float slot
    const int wrv   = 4 * wslot + ((c & 4) ? 1152 : 0);

    const char* rb0 = shm + rdv;
    const char* rb1 = shm + rdv + 2304;
    char*       wb0 = shm + wrv;
    char*       wb1 = shm + wrv + 2304;

    // ---- weights: rows r0..r0+3 at permuted col chunks (128 scalars) ----
    DECL8(A); DECL8(B); DECL8(C); DECL8(D);
    {
        const float* pA = Hw + (size_t)(r0 + 0) * NXc;
        const float* pB = Hw + (size_t)(r0 + 1) * NXc;
        const float* pC = Hw + (size_t)(r0 + 2) * NXc;
        const float* pD = Hw + (size_t)(r0 + 3) * NXc;
        LOAD8(A, pA); LOAD8(B, pB); LOAD8(C, pC); LOAD8(D, pD);
    }
    DECLK8(A); DECLK8(B); DECLK8(C); DECLK8(D);
    const float* uptr = inputs + (size_t)b * Tl * NUc + 8 * c;
    if (!USE_KU) {
        const float* q = Kw + (size_t)r0 * NUc + 8 * c;
        LOADK8(A,q); q += NUc; LOADK8(B,q); q += NUc;
        LOADK8(C,q); q += NUc; LOADK8(D,q);
    }

    const float bias = Hb[row_w];
    const float* kup = Ku + (size_t)b * Tl * NXc + NXc + row_w;  // Ku[b,1,row_w]
    float*       stp = states + (size_t)b * Tl * NXc + NXc + row_w;

    float bk;                                    // bias (+ku) for current step
    float4 Q0c;                                  // carried own-wave chunk
    {
        float h = h0[b * NXc + row_w];
        states[(size_t)b * Tl * NXc + row_w] = h;     // states[b,0,:]
        *(float*)wb0 = h;                             // buffer0, own image
        Q0c = *(const float4*)rb0;                    // own-wave chunk of h_0
        bk = USE_KU ? (bias + Ku[(size_t)b * Tl * NXc + row_w]) : bias;
        __syncthreads();
    }

#define STEPBODY(RB, WB, RBN) { \
    PIN8(A); PIN8(B); PIN8(C); PIN8(D); \
    if (!USE_KU) { PINK8(A); PINK8(B); PINK8(C); PINK8(D); } \
    float4 Q1 = *(const float4*)((RB) + 144); \
    float4 Q2 = *(const float4*)((RB) + 288); \
    float4 Q3 = *(const float4*)((RB) + 432); \
    float4 Q4 = *(const float4*)((RB) + 576); \
    float4 Q5 = *(const float4*)((RB) + 720); \
    float4 Q6 = *(const float4*)((RB) + 864); \
    float4 Q7 = *(const float4*)((RB) + 1008); \
    float kn_ = 0.f; float4 uu0, uu1; \
    if (USE_KU) { kn_ = *kup; kup += NXc; } \
    else { uu0 = *(const float4*)uptr; uu1 = *(const float4*)(uptr + 4); uptr += NUc; } \
    float aA0=0.f,aA1=0.f,aB0=0.f,aB1=0.f,aC0=0.f,aC1=0.f,aD0=0.f,aD1=0.f; \
    CHUNKF(0, Q0c); \
    if (!USE_KU) { FMAK8(A); FMAK8(B); FMAK8(C); FMAK8(D); } \
    CHUNKF(1, Q1); CHUNKF(2, Q2); CHUNKF(3, Q3); CHUNKF(4, Q4); \
    CHUNKF(5, Q5); CHUNKF(6, Q6); CHUNKF(7, Q7); \
    float sA = aA0 + aA1, sB = aB0 + aB1; \
    float sC = aC0 + aC1, sD = aD0 + aD1; \
    float rA, rB, rC, rD; \
    red8x4(sA, sB, sC, sD, rA, rB, rC, rD); \
    float x_ = (c & 1) ? rB : rA; \
    float y_ = (c & 1) ? rD : rC; \
    float v_ = (c & 2) ? y_ : x_; \
    float s_ = v_ + bk; \
    float h_ = s_ > 0.f ? s_ : 0.f; \
    *(float*)(WB) = h_;                    /* publish h (own image) */ \
    Q0c = *(const float4*)(RBN);           /* pre-read own-wave chunk */ \
    *stp = h_; stp += NXc;                 /* fire-and-forget states */ \
    bk = USE_KU ? (bias + kn_) : bias; \
    asm volatile("s_waitcnt lgkmcnt(1)\n\ts_barrier" ::: "memory"); \
}

    for (int tt = 0; tt < (Tl - 2) / 2; ++tt) {   // 2047 pairs = 4094 steps
        STEPBODY(rb0, wb1, rb1);
        STEPBODY(rb1, wb0, rb0);
    }
    STEPBODY(rb0, wb1, rb1);                      // final step -> 4095 total
#undef STEPBODY
}

// ---------------------------------------------------------------------------
// yest[row, g] = dot(states[row,:], out_w[g,:]) + out_b[g]
// ---------------------------------------------------------------------------
__global__ __launch_bounds__(512, 2) void yest2(const float* __restrict__ states,
                                                const float* __restrict__ ow,
                                                const float* __restrict__ obv,
                                                float* __restrict__ yest) {
    const int tid = threadIdx.x;
    const int c   = tid & 15;
    const int g   = tid >> 4;                    // 0..31

    float y0_,y1_,y2_,y3_,y4_,y5_,y6_,y7_,y8_,y9_,y10_,y11_,y12_,y13_,y14_,y15_;
    {
        const float* wr = ow + (size_t)g * NXc + 16 * c;
        float4 vA = *(const float4*)(wr + 0),  vB = *(const float4*)(wr + 4);
        float4 vC = *(const float4*)(wr + 8),  vD = *(const float4*)(wr + 12);
        y0_=vA.x; y1_=vA.y; y2_ =vA.z; y3_ =vA.w;
        y4_=vB.x; y5_=vB.y; y6_ =vB.z; y7_ =vB.w;
        y8_=vC.x; y9_=vC.y; y10_=vC.z; y11_=vC.w;
        y12_=vD.x;y13_=vD.y;y14_=vD.z; y15_=vD.w;
        KEEPF(y0_); KEEPF(y1_); KEEPF(y2_);  KEEPF(y3_);
        KEEPF(y4_); KEEPF(y5_); KEEPF(y6_);  KEEPF(y7_);
        KEEPF(y8_); KEEPF(y9_); KEEPF(y10_); KEEPF(y11_);
        KEEPF(y12_);KEEPF(y13_);KEEPF(y14_); KEEPF(y15_);
    }
    const float ob = obv[g];

    const int row0 = blockIdx.x * 128;
    for (int r = 0; r < 128; r += 2) {
        const float* s0p = states + (size_t)(row0 + r) * NXc + 16 * c;
        const float* s1p = s0p + NXc;
        float4 A0 = *(const float4*)(s0p + 0), A1 = *(const float4*)(s0p + 4);
        float4 A2 = *(const float4*)(s0p + 8), A3 = *(const float4*)(s0p + 12);
        float4 B0 = *(const float4*)(s1p + 0), B1 = *(const float4*)(s1p + 4);
        float4 B2 = *(const float4*)(s1p + 8), B3 = *(const float4*)(s1p + 12);
        float acc0 = y0_*A0.x + y1_*A0.y + y2_*A0.z + y3_*A0.w
                   + y4_*A1.x + y5_*A1.y + y6_*A1.z + y7_*A1.w
                   + y8_*A2.x + y9_*A2.y + y10_*A2.z + y11_*A2.w
                   + y12_*A3.x + y13_*A3.y + y14_*A3.z + y15_*A3.w;
        float acc1 = y0_*B0.x + y1_*B0.y + y2_*B0.z + y3_*B0.w
                   + y4_*B1.x + y5_*B1.y + y6_*B1.z + y7_*B1.w
                   + y8_*B2.x + y9_*B2.y + y10_*B2.z + y11_*B2.w
                   + y12_*B3.x + y13_*B3.y + y14_*B3.z + y15_*B3.w;
        acc0 = row_reduce16(acc0);
        acc1 = row_reduce16(acc1);
        if (c == 0) {
            yest[(size_t)(row0 + r)     * NYc + g] = acc0 + ob;
            yest[(size_t)(row0 + r + 1) * NYc + g] = acc1 + ob;
        }
    }
}

// ---------------------------------------------------------------------------
extern "C" void kernel_launch(void* const* d_in, const int* in_sizes, int n_in,
                              void* d_out, int out_size, void* d_ws, size_t ws_size,
                              hipStream_t stream) {
    const float* inputs = (const float*)d_in[0];   // [B,T,NU]
    const float* h0     = (const float*)d_in[1];   // [B,NX]
    const float* Hw     = (const float*)d_in[2];   // [NX,NX]
    const float* Hb     = (const float*)d_in[3];   // [NX]
    const float* Kw     = (const float*)d_in[4];   // [NX,NU]
    // d_in[5] = E_inv: identity; relu(x) @ I == relu(x) exactly.
    const float* ow     = (const float*)d_in[6];   // [NY,NX]
    const float* ob     = (const float*)d_in[7];   // [NY]

    float* yest   = (float*)d_out;                              // [B,T,NY]
    float* states = (float*)d_out + (size_t)Bsz * Tl * NYc;     // [B,T,NX]

    const size_t ku_bytes = (size_t)Bsz * Tl * NXc * sizeof(float);  // 64 MB
    const int    nrows    = Bsz * Tl;

    if (ws_size >= ku_bytes) {
        float* Ku = (float*)d_ws;
        ku_kernel<<<dim3(nrows / 64), dim3(256), 0, stream>>>(inputs, Kw, Ku);
        scan7<true><<<dim3(Bsz), dim3(512), 0, stream>>>(Ku, inputs, Kw, h0, Hw, Hb, states);
    } else {
        scan7<false><<<dim3(Bsz), dim3(512), 0, stream>>>(nullptr, inputs, Kw, h0, Hw, Hb, states);
    }
    yest2<<<dim3(nrows / 128), dim3(512), 0, stream>>>(states, ow, ob, yest);
}